// Round 3
// baseline (125.236 us; speedup 1.0000x reference)
//
#include <hip/hip_runtime.h>

typedef __attribute__((ext_vector_type(4))) int   int4v;
typedef __attribute__((ext_vector_type(4))) float float4v;

// XOR swizzle of the 16B slot within a 64B K-row (qA layout, round-0 proven).
__device__ __forceinline__ int swz(int row, int slot) {
    return slot ^ ((row ^ (row >> 2)) & 3);
}

// Bijective col permutation for qB16: spreads 64B-stride col accesses across banks.
__device__ __forceinline__ int pcol(int col) {
    return col ^ ((col >> 3) & 7);
}

// Exact replica of reference fake-quant grid index (IEEE div + round-half-even).
__device__ __forceinline__ int quant1(float x, float lo, float up, float scale) {
    float xc = fminf(fmaxf(x, lo), up);
    return (int)rintf((xc - lo) / scale);
}

__device__ __forceinline__ unsigned bsum(int p) {        // sum of 4 bytes (<=15 each)
    return ((unsigned)p * 0x01010101u) >> 24;
}

__global__ __launch_bounds__(256, 4) void qmm_kernel(
    const float* __restrict__ A, const float* __restrict__ B,
    const float* __restrict__ aLo, const float* __restrict__ aUp,
    const float* __restrict__ bLo, const float* __restrict__ bUp,
    float* __restrict__ Out)
{
    // qA: [row 0..255][16 ints] i8, k-contiguous, slot-swizzled (round-0 layout)
    __shared__ int   qA[256 * 16];
    // qB16: [lk 0..3][p(col)] -> 16B = k-bytes lk*16..lk*16+15 of col (B transposed)
    __shared__ int4v qB16[4][256];
    __shared__ float RAf[256];   // sA*lB*rowsum(qA[row]) + 32*lA*lB
    __shared__ float CBf[256];   // lA*sB*colsum(qB[col]) + 32*lA*lB

    const int tid = threadIdx.x;
    const int b   = blockIdx.x;

    const float lA = aLo[0], uA = aUp[0];
    const float lB = bLo[0], uB = bUp[0];
    const float sA  = (uA - lA) / 15.0f;
    const float sB  = (uB - lB) / 15.0f;
    const float sAB = sA * sB;

    const float4v* A4 = (const float4v*)(A + (size_t)b * 256 * 64);
    const float4v* B4 = (const float4v*)(B + (size_t)b * 64 * 256);
    float* outb = Out + (size_t)b * 256 * 256;

    // ---- stage A: dense coalesced float4 loads (1KB/instr), pack 4 x i8 -> int
    #pragma unroll
    for (int it = 0; it < 16; ++it) {
        int f = it * 256 + tid;            // float4 index 0..4095
        float4v v = A4[f];
        int q0 = quant1(v[0], lA, uA, sA);
        int q1 = quant1(v[1], lA, uA, sA);
        int q2 = quant1(v[2], lA, uA, sA);
        int q3 = quant1(v[3], lA, uA, sA);
        int p  = q0 | (q1 << 8) | (q2 << 16) | (q3 << 24);
        int row = f >> 4, chunk = f & 15;  // row 0..255, 16 ints per row
        qA[row * 16 + swz(row, chunk >> 2) * 4 + (chunk & 3)] = p;
    }

    // ---- stage B: dense coalesced loads, transpose in regs, b128 LDS writes
    //      thread (u=tid&63, w=tid>>6) owns cols 4u..4u+3, k = w*16 .. w*16+15
    {
        const int u = tid & 63, w = tid >> 6;
        int pk[4][4];                                  // [col c][int slot m]
        #pragma unroll
        for (int m = 0; m < 4; ++m) {
            float4v r0 = B4[(size_t)(w*16 + m*4 + 0) * 64 + u];
            float4v r1 = B4[(size_t)(w*16 + m*4 + 1) * 64 + u];
            float4v r2 = B4[(size_t)(w*16 + m*4 + 2) * 64 + u];
            float4v r3 = B4[(size_t)(w*16 + m*4 + 3) * 64 + u];
            #pragma unroll
            for (int c = 0; c < 4; ++c) {
                pk[c][m] =  quant1(r0[c], lB, uB, sB)        | (quant1(r1[c], lB, uB, sB) << 8) |
                           (quant1(r2[c], lB, uB, sB) << 16) | (quant1(r3[c], lB, uB, sB) << 24);
            }
        }
        #pragma unroll
        for (int c = 0; c < 4; ++c) {
            int col = u * 4 + c;
            int4v v = {pk[c][0], pk[c][1], pk[c][2], pk[c][3]};
            qB16[w][pcol(col)] = v;        // one b128 write, <=2-way banks
        }
    }
    __syncthreads();

    // ---- row sums of qA / col sums of qB -> RAf/CBf (thread tid = row/col tid)
    {
        unsigned sa = 0, sb = 0;
        #pragma unroll
        for (int sl = 0; sl < 4; ++sl) {
            int4v va = *(const int4v*)&qA[tid * 16 + swz(tid, sl) * 4];
            int4v vb = qB16[sl][pcol(tid)];
            sa += bsum(va[0]) + bsum(va[1]) + bsum(va[2]) + bsum(va[3]);
            sb += bsum(vb[0]) + bsum(vb[1]) + bsum(vb[2]) + bsum(vb[3]);
        }
        float c32 = 32.0f * lA * lB;
        RAf[tid] = sA * lB * (float)sa + c32;
        CBf[tid] = lA * sB * (float)sb + c32;
    }
    __syncthreads();

    // ---- compute: swapped operands -> lane (lr,lk) holds row wave*64+rt*16+lr,
    //      cols ct*16+lk*4..+3  => global_store_dwordx4
    const int lane = tid & 63, wave = tid >> 6;
    const int lr = lane & 15, lk = lane >> 4;

    int4v afrag[4];
    float RA[4];
    #pragma unroll
    for (int rt = 0; rt < 4; ++rt) {
        int row = wave * 64 + rt * 16 + lr;
        afrag[rt] = *(const int4v*)&qA[row * 16 + swz(row, lk) * 4];
        RA[rt]    = RAf[row];
    }

    const int4v z4 = {0, 0, 0, 0};
    #pragma unroll 4
    for (int ct = 0; ct < 16; ++ct) {
        int4v   bfrag = qB16[lk][pcol(ct * 16 + lr)];
        float4v cb    = *(const float4v*)&CBf[ct * 16 + lk * 4];
        #pragma unroll
        for (int rt = 0; rt < 4; ++rt) {
            int4v acc = __builtin_amdgcn_mfma_i32_16x16x64_i8(bfrag, afrag[rt], z4, 0, 0, 0);
            int row = wave * 64 + rt * 16 + lr;
            float4v o;
            o[0] = fmaf(sAB, (float)acc[0], RA[rt] + cb[0]);
            o[1] = fmaf(sAB, (float)acc[1], RA[rt] + cb[1]);
            o[2] = fmaf(sAB, (float)acc[2], RA[rt] + cb[2]);
            o[3] = fmaf(sAB, (float)acc[3], RA[rt] + cb[3]);
            *(float4v*)&outb[(size_t)row * 256 + ct * 16 + lk * 4] = o;
        }
    }
}

extern "C" void kernel_launch(void* const* d_in, const int* in_sizes, int n_in,
                              void* d_out, int out_size, void* d_ws, size_t ws_size,
                              hipStream_t stream) {
    const float* A   = (const float*)d_in[0];
    const float* B   = (const float*)d_in[1];
    const float* aLo = (const float*)d_in[2];
    const float* aUp = (const float*)d_in[3];
    const float* bLo = (const float*)d_in[4];
    const float* bUp = (const float*)d_in[5];
    float* Out = (float*)d_out;

    int batches = in_sizes[0] / (256 * 64);   // 128*8 = 1024
    qmm_kernel<<<batches, 256, 0, stream>>>(A, B, aLo, aUp, bLo, bUp, Out);
}

// Round 4
// 98.595 us; speedup vs baseline: 1.2702x; 1.2702x over previous
//
#include <hip/hip_runtime.h>

typedef __attribute__((ext_vector_type(4))) int   int4v;
typedef __attribute__((ext_vector_type(4))) float float4v;

// XOR swizzle of the 16B slot within a 64B K-row (round-0 proven layout).
__device__ __forceinline__ int swz(int row, int slot) {
    return slot ^ ((row ^ (row >> 2)) & 3);
}

// Fake-quant grid index, bit-exact vs reference's rint((clamp(x)-lo)/scale):
// fast path multiplies by reciprocal (err <= ~5e-6 on m in [0,15]); if ANY of
// the 4 values is within 1e-4 of a rounding tie (n+0.5), redo all 4 with true
// IEEE division. 20x safety margin; slow path ~5% of groups -> ~free.
__device__ __forceinline__ int4v quant4(float4v v, float lo, float up,
                                        float scale, float inv) {
    float t0 = fminf(fmaxf(v[0], lo), up) - lo;
    float t1 = fminf(fmaxf(v[1], lo), up) - lo;
    float t2 = fminf(fmaxf(v[2], lo), up) - lo;
    float t3 = fminf(fmaxf(v[3], lo), up) - lo;
    float m0 = t0 * inv, m1 = t1 * inv, m2 = t2 * inv, m3 = t3 * inv;
    float r0 = rintf(m0), r1 = rintf(m1), r2 = rintf(m2), r3 = rintf(m3);
    float d0 = fabsf(fabsf(m0 - r0) - 0.5f);
    float d1 = fabsf(fabsf(m1 - r1) - 0.5f);
    float d2 = fabsf(fabsf(m2 - r2) - 0.5f);
    float d3 = fabsf(fabsf(m3 - r3) - 0.5f);
    if (fminf(fminf(d0, d1), fminf(d2, d3)) < 1e-4f) {   // rare tie-suspect
        r0 = rintf(t0 / scale); r1 = rintf(t1 / scale);
        r2 = rintf(t2 / scale); r3 = rintf(t3 / scale);
    }
    int4v q = {(int)r0, (int)r1, (int)r2, (int)r3};
    return q;
}

__device__ __forceinline__ unsigned bsum(int p) {        // sum of 4 bytes (<=15 each)
    return ((unsigned)p * 0x01010101u) >> 24;
}

__global__ __launch_bounds__(256, 4) void qmm_kernel(
    const float* __restrict__ A, const float* __restrict__ B,
    const float* __restrict__ aLo, const float* __restrict__ aUp,
    const float* __restrict__ bLo, const float* __restrict__ bUp,
    float* __restrict__ Out)
{
    // qA: [row 0..255][k 0..63] i8 (int = 4 consecutive k), slot-swizzled
    // qB: B^T -> [col 0..255][k 0..63] i8, same layout
    __shared__ int   qA[256 * 16];
    __shared__ int   qB[256 * 16];
    __shared__ float RAf[256];   // sA*lB*rowsum(qA[i]) + 32*lA*lB
    __shared__ float CBf[256];   // lA*sB*colsum(qB[j]) + 32*lA*lB

    const int tid = threadIdx.x;
    const int b   = blockIdx.x;

    const float lA = aLo[0], uA = aUp[0];
    const float lB = bLo[0], uB = bUp[0];
    const float sA  = (uA - lA) / 15.0f;
    const float sB  = (uB - lB) / 15.0f;
    const float iA  = 1.0f / sA;
    const float iB  = 1.0f / sB;
    const float sAB = sA * sB;

    const float4v* A4 = (const float4v*)(A + (size_t)b * 256 * 64);
    const float4v* B4 = (const float4v*)(B + (size_t)b * 64 * 256);
    float* outb = Out + (size_t)b * 256 * 256;

    // ---- stage A: dense coalesced float4 loads (1KB/instr), pack 4 x i8 -> int
    #pragma unroll
    for (int it = 0; it < 16; ++it) {
        int f = it * 256 + tid;            // float4 index 0..4095
        float4v v = A4[f];
        int4v q = quant4(v, lA, uA, sA, iA);
        int p  = q[0] | (q[1] << 8) | (q[2] << 16) | (q[3] << 24);
        int row = f >> 4, chunk = f & 15;  // row 0..255, 16 ints per row
        qA[row * 16 + swz(row, chunk >> 2) * 4 + (chunk & 3)] = p;
    }

    // ---- stage B: coalesced loads of 4x4 fp32 tile, transpose in regs ----
    const int u  = tid & 63;   // column group: cols 4u..4u+3
    const int kg = tid >> 6;   // wave id -> 4-byte offset inside 16B k-slot
    #pragma unroll
    for (int kb = 0; kb < 4; ++kb) {
        int k0 = kb * 16 + kg * 4;         // k rows k0..k0+3
        int4v q0 = quant4(B4[(size_t)(k0 + 0) * 64 + u], lB, uB, sB, iB);
        int4v q1 = quant4(B4[(size_t)(k0 + 1) * 64 + u], lB, uB, sB, iB);
        int4v q2 = quant4(B4[(size_t)(k0 + 2) * 64 + u], lB, uB, sB, iB);
        int4v q3 = quant4(B4[(size_t)(k0 + 3) * 64 + u], lB, uB, sB, iB);
        #pragma unroll
        for (int c = 0; c < 4; ++c) {
            int col = u * 4 + c;
            int p = q0[c] | (q1[c] << 8) | (q2[c] << 16) | (q3[c] << 24);
            qB[col * 16 + swz(col, kb) * 4 + kg] = p;
        }
    }

    __syncthreads();

    // ---- row sums of qA / col sums of B (rows of qB), byte-sum trick ----
    {
        unsigned sa = 0, sb = 0;
        #pragma unroll
        for (int j = 0; j < 16; ++j) {
            unsigned pa = (unsigned)qA[tid * 16 + swz(tid, j >> 2) * 4 + (j & 3)];
            unsigned pb = (unsigned)qB[tid * 16 + swz(tid, j >> 2) * 4 + (j & 3)];
            sa += bsum(pa);
            sb += bsum(pb);
        }
        float c32 = 32.0f * lA * lB;
        RAf[tid] = sA * lB * (float)sa + c32;
        CBf[tid] = lA * sB * (float)sb + c32;
    }
    __syncthreads();

    // ---- compute: each wave owns 64 rows x all 256 cols, 16x16x64 MFMA ----
    const int wave = tid >> 6, lane = tid & 63;
    const int lr = lane & 15;   // fragment row (A) / col (B) / out col
    const int lk = lane >> 4;   // k-block 0..3 (16 i8 each)

    int4v afrag[4];
    #pragma unroll
    for (int rt = 0; rt < 4; ++rt) {
        int row = wave * 64 + rt * 16 + lr;
        afrag[rt] = *(const int4v*)&qA[row * 16 + swz(row, lk) * 4];
    }

    #pragma unroll 4
    for (int ct = 0; ct < 16; ++ct) {
        int col = ct * 16 + lr;
        int4v bfrag = *(const int4v*)&qB[col * 16 + swz(col, lk) * 4];
        float cb = CBf[col];               // out col == lane&15 == lr
        #pragma unroll
        for (int rt = 0; rt < 4; ++rt) {
            int4v acc = {0, 0, 0, 0};
            acc = __builtin_amdgcn_mfma_i32_16x16x64_i8(afrag[rt], bfrag, acc, 0, 0, 0);
            int orow = wave * 64 + rt * 16 + lk * 4;   // C/D: row=(lane>>4)*4+reg
            #pragma unroll
            for (int r = 0; r < 4; ++r) {
                outb[(size_t)(orow + r) * 256 + col] =
                    sAB * (float)acc[r] + RAf[orow + r] + cb;
            }
        }
    }
}

extern "C" void kernel_launch(void* const* d_in, const int* in_sizes, int n_in,
                              void* d_out, int out_size, void* d_ws, size_t ws_size,
                              hipStream_t stream) {
    const float* A   = (const float*)d_in[0];
    const float* B   = (const float*)d_in[1];
    const float* aLo = (const float*)d_in[2];
    const float* aUp = (const float*)d_in[3];
    const float* bLo = (const float*)d_in[4];
    const float* bUp = (const float*)d_in[5];
    float* Out = (float*)d_out;

    int batches = in_sizes[0] / (256 * 64);   // 128*8 = 1024
    qmm_kernel<<<batches, 256, 0, stream>>>(A, B, aLo, aUp, bLo, bUp, Out);
}